// Round 7
// baseline (535.326 us; speedup 1.0000x reference)
//
#include <hip/hip_runtime.h>
#include <math.h>

#define BB 8
#define TT 288
#define NN 2000
#define FLEN 145
#define EE 128
#define IDD 16
#define HH 128
#define DKK 144
#define KTOP 20

typedef _Float16 half8 __attribute__((ext_vector_type(8)));
typedef float f32x4 __attribute__((ext_vector_type(4)));
typedef unsigned short ushort_t;

// ---- workspace layout (float offsets) ----
#define OFF_TW  ((size_t)0)
#define SZ_TW   ((size_t)TT*FLEN*2)
#define OFF_XF  (OFF_TW + SZ_TW)
#define SZ_XF   ((size_t)BB*FLEN*NN)
#define OFF_ICN (OFF_XF + SZ_XF)
#define OFF_IRN (OFF_ICN + (size_t)BB*FLEN)
#define OFF_XE  (OFF_IRN + (size_t)BB*NN)   // after k_x1 consumes xe, region is reused as x1 hi/lo fp16 (fragment-tiled)
#define SZ_BNH  ((size_t)BB*NN*HH)
#define OFF_X1  (OFF_XE + SZ_BNH)
#define OFF_ADP (OFF_X1 + SZ_BNH)           // holds adp hi/lo fp16 (fragment-tiled), never fp32
#define OFF_CSW (OFF_ADP + SZ_BNH)
#define OFF_LNS (OFF_CSW + HH)
#define OFF_LNF (OFF_LNS + 16)

// Fragment-tiled hi/lo layout (NN = 125*16 exactly):
//   ushort offset = (b*125 + (n>>4))*4096 + hl*2048 + (k>>5)*512
//                 + ((k>>3)&3)*128 + (n&15)*8 + (k&7)
// A wave's MFMA fragment load (lane = quad*16+r16) is ONE contiguous 1KB read.

__device__ __forceinline__ float wredSum(float v) {
#pragma unroll
  for (int o = 32; o > 0; o >>= 1) v += __shfl_down(v, o, 64);
  return v;
}
// butterfly variants: result valid in ALL lanes
__device__ __forceinline__ float wredSumAll(float v) {
#pragma unroll
  for (int o = 32; o > 0; o >>= 1) v += __shfl_xor(v, o, 64);
  return v;
}

// fp16 hi/lo split: v = hi + lo + O(2^-22 * v)
__device__ __forceinline__ void split16(float v, ushort_t& hi, ushort_t& lo) {
  _Float16 h = (_Float16)v;
  _Float16 l = (_Float16)(v - (float)h);
  union { _Float16 f; ushort_t u; } a, b;
  a.f = h; b.f = l;
  hi = a.u; lo = b.u;
}

// twiddles (exact int reduction of angle) + merged k_init work in block 0
__global__ void k_tw(const float* __restrict__ Wx, float* __restrict__ tw,
                     float* __restrict__ csw, float* __restrict__ lns) {
  if (blockIdx.x == 0 && threadIdx.x < 128) {
    int k = threadIdx.x;
    float s = 0.f;
    for (int h = 0; h < HH; ++h) s += Wx[h * HH + k];
    csw[k] = s;
    if (k < 16) lns[k] = 0.f;
  }
  int id = blockIdx.x * 256 + threadIdx.x;
  if (id >= TT * FLEN) return;
  int t = id / FLEN, f = id % FLEN;
  int r = (t * f) % TT;
  double th = -2.0 * 3.14159265358979323846 * (double)r / (double)TT;
  tw[2 * id]     = (float)cos(th);
  tw[2 * id + 1] = (float)sin(th);
}

// xf[b][f][n] = |rfft(x[b,:,n])[f]|
__global__ void k_dft(const float* __restrict__ x, const float* __restrict__ tw,
                      float* __restrict__ xf) {
  __shared__ __align__(16) float Xs[16][128];
  __shared__ __align__(16) float TWs[16][32][2];
  const int b = blockIdx.z;
  const int f0 = blockIdx.y * 32;
  const int n0 = blockIdx.x * 128;
  const int tid = threadIdx.x;
  const int tn = tid & 31;
  const int tf = tid >> 5;
  float ar[4][4] = {}, ai[4][4] = {};
  for (int t0 = 0; t0 < TT; t0 += 16) {
    __syncthreads();
    for (int l = tid; l < 512; l += 256) {
      int row = l >> 5, q = l & 31;
      int n = n0 + q * 4;
      const float* src = x + ((size_t)b * TT + (t0 + row)) * NN + n;
      float4 v = make_float4(0, 0, 0, 0);
      if (n + 3 < NN) v = *(const float4*)src;
      else {
        if (n + 0 < NN) v.x = src[0];
        if (n + 1 < NN) v.y = src[1];
        if (n + 2 < NN) v.z = src[2];
        if (n + 3 < NN) v.w = src[3];
      }
      *(float4*)&Xs[row][q * 4] = v;
    }
    for (int l = tid; l < 512; l += 256) {
      int row = l >> 5, ff = l & 31;
      int f = f0 + ff;
      float2 cs = make_float2(0, 0);
      if (f < FLEN) cs = *(const float2*)&tw[((size_t)(t0 + row) * FLEN + f) * 2];
      *(float2*)&TWs[row][ff][0] = cs;
    }
    __syncthreads();
#pragma unroll 4
    for (int t = 0; t < 16; ++t) {
      float4 xv = *(float4*)&Xs[t][tn * 4];
      float xx[4] = {xv.x, xv.y, xv.z, xv.w};
      float4 p0 = *(float4*)&TWs[t][tf * 4][0];
      float4 p1 = *(float4*)&TWs[t][tf * 4 + 2][0];
      float c[4] = {p0.x, p0.z, p1.x, p1.z};
      float s[4] = {p0.y, p0.w, p1.y, p1.w};
#pragma unroll
      for (int i = 0; i < 4; ++i)
#pragma unroll
        for (int j = 0; j < 4; ++j) {
          ar[i][j] = fmaf(xx[j], c[i], ar[i][j]);
          ai[i][j] = fmaf(xx[j], s[i], ai[i][j]);
        }
    }
  }
#pragma unroll
  for (int i = 0; i < 4; ++i) {
    int f = f0 + tf * 4 + i;
    if (f >= FLEN) continue;
    float* dst = &xf[((size_t)b * FLEN + f) * NN];
    float o[4];
#pragma unroll
    for (int j = 0; j < 4; ++j)
      o[j] = sqrtf(ar[i][j] * ar[i][j] + ai[i][j] * ai[i][j]);
    int n = n0 + tn * 4;
    if (n + 3 < NN) *(float4*)&dst[n] = make_float4(o[0], o[1], o[2], o[3]);
    else {
#pragma unroll
      for (int j = 0; j < 4; ++j) if (n + j < NN) dst[n + j] = o[j];
    }
  }
}

__global__ void k_colnorm(const float* __restrict__ xf, float* __restrict__ icn) {
  __shared__ float sc[4];
  int bf = blockIdx.x;
  const float* rowp = xf + (size_t)bf * NN;
  float s = 0.f;
  for (int i = threadIdx.x; i < NN; i += 256) { float v = rowp[i]; s = fmaf(v, v, s); }
  s = wredSum(s);
  int lane = threadIdx.x & 63, w = threadIdx.x >> 6;
  if (lane == 0) sc[w] = s;
  __syncthreads();
  if (threadIdx.x == 0)
    icn[bf] = 1.f / fmaxf(sqrtf(sc[0] + sc[1] + sc[2] + sc[3]), 1e-12f);
}

__global__ void k_rownorm(const float* __restrict__ xf, const float* __restrict__ icn,
                          float* __restrict__ irn) {
  int b = blockIdx.y;
  int n = blockIdx.x * 256 + threadIdx.x;
  if (n >= NN) return;
  float s = 0.f;
  for (int f = 0; f < FLEN; ++f) {
    float v = xf[((size_t)b * FLEN + f) * NN + n] * icn[b * FLEN + f];
    s = fmaf(v, v, s);
  }
  irn[b * NN + n] = 1.f / fmaxf(sqrtf(s), 1e-12f);
}

__global__ void k_xe(const float* __restrict__ xf, const float* __restrict__ icn,
                     const float* __restrict__ irn, const float* __restrict__ Ex,
                     float* __restrict__ xe) {
  __shared__ __align__(16) float As[16][64];
  __shared__ __align__(16) float Bs[16][128];
  const int b = blockIdx.y;
  const int n0 = blockIdx.x * 64;
  const int tid = threadIdx.x;
  const int tn = tid >> 4, te = tid & 15;
  float acc[4][8] = {};
  for (int f0 = 0; f0 < 160; f0 += 16) {
    __syncthreads();
    {
      int kt = tid >> 4, q = tid & 15;
      int f = f0 + kt;
      int n = n0 + q * 4;
      float4 v = make_float4(0, 0, 0, 0);
      if (f < FLEN) {
        float ic = icn[b * FLEN + f];
        const float* src = &xf[((size_t)b * FLEN + f) * NN + n];
        if (n + 3 < NN) v = *(const float4*)src;
        else {
          if (n + 0 < NN) v.x = src[0];
          if (n + 1 < NN) v.y = src[1];
          if (n + 2 < NN) v.z = src[2];
          if (n + 3 < NN) v.w = src[3];
        }
        v.x *= ic; v.y *= ic; v.z *= ic; v.w *= ic;
      }
      *(float4*)&As[kt][q * 4] = v;
    }
    for (int l = tid; l < 512; l += 256) {
      int kt = l >> 5, q = l & 31;
      int f = f0 + kt;
      float4 v = make_float4(0, 0, 0, 0);
      if (f < FLEN) v = *(const float4*)&Ex[(size_t)f * EE + q * 4];
      *(float4*)&Bs[kt][q * 4] = v;
    }
    __syncthreads();
#pragma unroll
    for (int k = 0; k < 16; ++k) {
      float4 a  = *(float4*)&As[k][tn * 4];
      float4 b0 = *(float4*)&Bs[k][te * 4];
      float4 b1 = *(float4*)&Bs[k][64 + te * 4];
      float av[4] = {a.x, a.y, a.z, a.w};
      float bv[8] = {b0.x, b0.y, b0.z, b0.w, b1.x, b1.y, b1.z, b1.w};
#pragma unroll
      for (int i = 0; i < 4; ++i)
#pragma unroll
        for (int j = 0; j < 8; ++j)
          acc[i][j] = fmaf(av[i], bv[j], acc[i][j]);
    }
  }
#pragma unroll
  for (int i = 0; i < 4; ++i) {
    int n = n0 + tn * 4 + i;
    if (n >= NN) continue;
    float sc = irn[b * NN + n];
    float* dst = &xe[((size_t)b * NN + n) * EE];
    *(float4*)&dst[te * 4] =
        make_float4(acc[i][0] * sc, acc[i][1] * sc, acc[i][2] * sc, acc[i][3] * sc);
    *(float4*)&dst[64 + te * 4] =
        make_float4(acc[i][4] * sc, acc[i][5] * sc, acc[i][6] * sc, acc[i][7] * sc);
  }
}

// x1 = relu([xe|nodes] . Wd[n]); emits x1 hi/lo fp16 fragment-tiled into dead xe region.
__global__ void k_x1(const float* xe, const float* __restrict__ nodes,
                     const float* __restrict__ Wd, float* __restrict__ x1,
                     ushort_t* x1hl) {
  __shared__ __align__(16) float xk[8][DKK];
  __shared__ float red[4][32][33];
  const int n = blockIdx.x;
  const int tid = threadIdx.x;
  {
    int b = tid >> 5, q = tid & 31;
    *(float4*)&xk[b][q * 4] = *(const float4*)&xe[((size_t)b * NN + n) * EE + q * 4];
  }
  if (tid < 128) {
    int b = tid >> 4, i = tid & 15;
    xk[b][EE + i] = nodes[(size_t)n * IDD + i];
  }
  __syncthreads();
  const int h4 = tid & 31;
  const int dg = tid >> 5;
  float acc[8][4] = {};
  for (int d = dg; d < DKK; d += 8) {
    float4 wv = *(const float4*)&Wd[((size_t)n * DKK + d) * HH + h4 * 4];
#pragma unroll
    for (int b = 0; b < 8; ++b) {
      float xv = xk[b][d];
      acc[b][0] = fmaf(xv, wv.x, acc[b][0]);
      acc[b][1] = fmaf(xv, wv.y, acc[b][1]);
      acc[b][2] = fmaf(xv, wv.z, acc[b][2]);
      acc[b][3] = fmaf(xv, wv.w, acc[b][3]);
    }
  }
#pragma unroll
  for (int b = 0; b < 8; ++b)
#pragma unroll
    for (int j = 0; j < 4; ++j)
      acc[b][j] += __shfl_xor(acc[b][j], 32, 64);
  const int wv_ = tid >> 6, lane = tid & 63;
  if (lane < 32) {
#pragma unroll
    for (int b = 0; b < 8; ++b)
#pragma unroll
      for (int j = 0; j < 4; ++j)
        red[wv_][lane][b * 4 + j] = acc[b][j];
  }
  __syncthreads();
  const size_t tbase = (size_t)(n >> 4) * 4096 + (size_t)(n & 15) * 8;
#pragma unroll
  for (int o = 0; o < 4; ++o) {
    int idx = tid + o * 256;
    int b = idx >> 7, h = idx & 127;
    float s = red[0][h >> 2][b * 4 + (h & 3)] + red[1][h >> 2][b * 4 + (h & 3)] +
              red[2][h >> 2][b * 4 + (h & 3)] + red[3][h >> 2][b * 4 + (h & 3)];
    s = fmaxf(s, 0.f);
    x1[((size_t)b * NN + n) * HH + h] = s;
    ushort_t hi, lo;
    split16(s, hi, lo);
    size_t slot = (size_t)b * (125 * 4096) + tbase +
                  (size_t)((h >> 5) * 512 + ((h >> 3) & 3) * 128 + (h & 7));
    x1hl[slot] = hi;
    x1hl[slot + 2048] = lo;
  }
}

__global__ void k_ln_stats(const float* __restrict__ x1, float* __restrict__ lns) {
  __shared__ float sc[4], sc2[4];
  int b = blockIdx.y, chunk = blockIdx.x;
  const float* base = x1 + (size_t)b * NN * HH + (size_t)chunk * 8000;
  float s = 0.f, s2 = 0.f;
  for (int i = threadIdx.x; i < 8000; i += 256) {
    float v = base[i];
    s += v; s2 = fmaf(v, v, s2);
  }
  s = wredSum(s); s2 = wredSum(s2);
  int lane = threadIdx.x & 63, w = threadIdx.x >> 6;
  if (lane == 0) { sc[w] = s; sc2[w] = s2; }
  __syncthreads();
  if (threadIdx.x == 0) {
    atomicAdd(&lns[b], sc[0] + sc[1] + sc[2] + sc[3]);
    atomicAdd(&lns[8 + b], sc2[0] + sc2[1] + sc2[2] + sc2[3]);
  }
}

// adp = ((x1 . Wx) - mu*colsumW) * inv_sd, fp16 hi/lo fragment-tiled.
// LN-final (mu/isd from raw sums) inlined per block -- bit-identical arithmetic.
__global__ void k_adp(const float* __restrict__ x1, const float* __restrict__ Wx,
                      const float* __restrict__ csw, const float* __restrict__ lns,
                      ushort_t* __restrict__ adphl) {
  __shared__ __align__(16) float As[16][64];
  __shared__ __align__(16) float Bs[16][128];
  const int r0 = blockIdx.x * 64;
  const int tid = threadIdx.x;
  const int tn = tid >> 4, te = tid & 15;
  float acc[4][8] = {};
  for (int k0 = 0; k0 < HH; k0 += 16) {
    __syncthreads();
    {
      int rr = tid >> 2, kq = tid & 3;
      float4 v = *(const float4*)&x1[(size_t)(r0 + rr) * HH + k0 + kq * 4];
      As[kq * 4 + 0][rr] = v.x;
      As[kq * 4 + 1][rr] = v.y;
      As[kq * 4 + 2][rr] = v.z;
      As[kq * 4 + 3][rr] = v.w;
    }
    for (int l = tid; l < 512; l += 256) {
      int kt = l >> 5, q = l & 31;
      *(float4*)&Bs[kt][q * 4] = *(const float4*)&Wx[(size_t)(k0 + kt) * HH + q * 4];
    }
    __syncthreads();
#pragma unroll
    for (int k = 0; k < 16; ++k) {
      float4 a  = *(float4*)&As[k][tn * 4];
      float4 b0 = *(float4*)&Bs[k][te * 4];
      float4 b1 = *(float4*)&Bs[k][64 + te * 4];
      float av[4] = {a.x, a.y, a.z, a.w};
      float bv[8] = {b0.x, b0.y, b0.z, b0.w, b1.x, b1.y, b1.z, b1.w};
#pragma unroll
      for (int i = 0; i < 4; ++i)
#pragma unroll
        for (int j = 0; j < 8; ++j)
          acc[i][j] = fmaf(av[i], bv[j], acc[i][j]);
    }
  }
  float4 c0 = *(const float4*)&csw[te * 4];
  float4 c1 = *(const float4*)&csw[64 + te * 4];
  float cw[8] = {c0.x, c0.y, c0.z, c0.w, c1.x, c1.y, c1.z, c1.w};
  const int c0k = te * 4, c1k = 64 + te * 4;
  const size_t o0r = (size_t)((c0k >> 5) * 512 + ((c0k >> 3) & 3) * 128 + (c0k & 7));
  const size_t o1r = (size_t)((c1k >> 5) * 512 + ((c1k >> 3) & 3) * 128 + (c1k & 7));
#pragma unroll
  for (int i = 0; i < 4; ++i) {
    int r = r0 + tn * 4 + i;
    int b = r / NN, n = r % NN;
    float cnt = (float)(NN * HH);
    float mu = lns[b] / cnt;
    float var = fmaxf(lns[8 + b] / cnt - mu * mu, 0.f);
    float isd = 1.f / sqrtf(var + 1e-8f);
    ushort_t hi[8], lo[8];
#pragma unroll
    for (int j = 0; j < 8; ++j) {
      float o = (acc[i][j] - mu * cw[j]) * isd;
      split16(o, hi[j], lo[j]);
    }
    size_t slot = (size_t)b * (125 * 4096) + (size_t)(n >> 4) * 4096 +
                  (size_t)(n & 15) * 8;
    ushort4 u;
    u.x = hi[0]; u.y = hi[1]; u.z = hi[2]; u.w = hi[3];
    *(ushort4*)&adphl[slot + o0r] = u;
    u.x = hi[4]; u.y = hi[5]; u.z = hi[6]; u.w = hi[7];
    *(ushort4*)&adphl[slot + o1r] = u;
    u.x = lo[0]; u.y = lo[1]; u.z = lo[2]; u.w = lo[3];
    *(ushort4*)&adphl[slot + 2048 + o0r] = u;
    u.x = lo[4]; u.y = lo[5]; u.z = lo[6]; u.w = lo[7];
    *(ushort4*)&adphl[slot + 2048 + o1r] = u;
  }
}

// ========== FUSED adj GEMM + topk-mask + softmax (register-resident) =========
// Block = 16 rows (one A-tile) x all 2000 m, 8 waves. Wave w owns m-tiles
// {w, w+8, ..., w+120} -> V[16] f32x4 registers (rows quad*4+reg, col r16).
// The 128MB fp32 adj intermediate never exists. Topk runs DISTRIBUTED:
// per-row counts/max via 16-lane shfl groups + small LDS matrix + barriers
// (all integer-count decisions -> bit-identical selection vs k_topsm);
// candidates compacted via LDS atomics (order-independent: sort ties on
// global column index); wave w sorts rows 2w,2w+1; all waves write their
// own fragments with per-row params.
__global__ __launch_bounds__(512, 2) void k_adjsm(
    const ushort_t* __restrict__ adphl, const ushort_t* __restrict__ x1hl,
    float* __restrict__ out) {
  __shared__ float wmax[8][16], wcnt0[8][16], wcntB[8][16], wexp[8][16];
  __shared__ int doneP[16];
  __shared__ int candCnt[16];
  __shared__ float candV[16][64];
  __shared__ int candI[16][64];
  __shared__ float pthr[16], pm[16], pinv[16], pdef[16];

  const int b = blockIdx.y;
  const int tA = blockIdx.x;
  const int n0 = tA * 16;
  const int tid = threadIdx.x;
  const int w = tid >> 6;
  const int lane = tid & 63;
  const int quad = lane >> 4, r16 = lane & 15;
  const int lq = quad * 128 + r16 * 8;

  // ---- phase 1: GEMM (identical MFMA chain to k_adjT -> bit-identical adj) --
  half8 Ah[4], Al[4];
  {
    const ushort_t* abase = adphl + ((size_t)(b * 125 + tA)) * 4096 + lq;
#pragma unroll
    for (int ks = 0; ks < 4; ++ks) {
      Ah[ks] = *(const half8*)(abase + ks * 512);
      Al[ks] = *(const half8*)(abase + 2048 + ks * 512);
    }
  }
  const ushort_t* Bb = x1hl + (size_t)b * (125 * 4096) + lq;
  f32x4 V[16];
  half8 Bh0[4], Bl0[4], Bh1[4], Bl1[4];

#define LOADB(I, BH, BL)                                                      \
  {                                                                           \
    int tl_ = w + 8 * (I);                                                    \
    if (tl_ > 124) tl_ = 124;                                                 \
    const ushort_t* bb_ = Bb + (size_t)tl_ * 4096;                            \
    BH[0] = *(const half8*)(bb_);        BL[0] = *(const half8*)(bb_ + 2048); \
    BH[1] = *(const half8*)(bb_ + 512);  BL[1] = *(const half8*)(bb_ + 2560); \
    BH[2] = *(const half8*)(bb_ + 1024); BL[2] = *(const half8*)(bb_ + 3072); \
    BH[3] = *(const half8*)(bb_ + 1536); BL[3] = *(const half8*)(bb_ + 3584); \
  }

#define STEP(I, BH, BL, BH2, BL2)                                             \
  {                                                                           \
    if ((I) < 15) LOADB((I) + 1, BH2, BL2);                                   \
    __builtin_amdgcn_sched_barrier(0);                                        \
    f32x4 acc = (f32x4){0.f, 0.f, 0.f, 0.f};                                  \
    _Pragma("unroll")                                                         \
    for (int ks = 0; ks < 4; ++ks) {                                          \
      acc = __builtin_amdgcn_mfma_f32_16x16x32_f16(Ah[ks], BH[ks], acc, 0, 0, 0); \
      acc = __builtin_amdgcn_mfma_f32_16x16x32_f16(Ah[ks], BL[ks], acc, 0, 0, 0); \
      acc = __builtin_amdgcn_mfma_f32_16x16x32_f16(Al[ks], BH[ks], acc, 0, 0, 0); \
    }                                                                         \
    bool vld_ = (w + 8 * (I)) <= 124;                                         \
    _Pragma("unroll")                                                         \
    for (int reg = 0; reg < 4; ++reg)                                         \
      V[(I)][reg] = vld_ ? fmaxf(acc[reg], 0.f) : -1.f;                       \
  }

  LOADB(0, Bh0, Bl0);
  STEP(0,  Bh0, Bl0, Bh1, Bl1);
  STEP(1,  Bh1, Bl1, Bh0, Bl0);
  STEP(2,  Bh0, Bl0, Bh1, Bl1);
  STEP(3,  Bh1, Bl1, Bh0, Bl0);
  STEP(4,  Bh0, Bl0, Bh1, Bl1);
  STEP(5,  Bh1, Bl1, Bh0, Bl0);
  STEP(6,  Bh0, Bl0, Bh1, Bl1);
  STEP(7,  Bh1, Bl1, Bh0, Bl0);
  STEP(8,  Bh0, Bl0, Bh1, Bl1);
  STEP(9,  Bh1, Bl1, Bh0, Bl0);
  STEP(10, Bh0, Bl0, Bh1, Bl1);
  STEP(11, Bh1, Bl1, Bh0, Bl0);
  STEP(12, Bh0, Bl0, Bh1, Bl1);
  STEP(13, Bh1, Bl1, Bh0, Bl0);
  STEP(14, Bh0, Bl0, Bh1, Bl1);
  STEP(15, Bh1, Bl1, Bh0, Bl0);
#undef STEP
#undef LOADB

  // ---- round A: per-row max + positive count (exact, order-independent) ----
  float mx4[4] = {-1.f, -1.f, -1.f, -1.f}, cp4[4] = {0.f, 0.f, 0.f, 0.f};
#pragma unroll
  for (int i = 0; i < 16; ++i)
#pragma unroll
    for (int reg = 0; reg < 4; ++reg) {
      mx4[reg] = fmaxf(mx4[reg], V[i][reg]);
      cp4[reg] += (V[i][reg] > 0.f) ? 1.f : 0.f;
    }
#pragma unroll
  for (int o = 8; o > 0; o >>= 1)
#pragma unroll
    for (int reg = 0; reg < 4; ++reg) {
      mx4[reg] = fmaxf(mx4[reg], __shfl_xor(mx4[reg], o, 64));
      cp4[reg] += __shfl_xor(cp4[reg], o, 64);
    }
  if (r16 == 0) {
#pragma unroll
    for (int reg = 0; reg < 4; ++reg) {
      wmax[w][quad * 4 + reg] = mx4[reg];
      wcnt0[w][quad * 4 + reg] = cp4[reg];
    }
  }
  __syncthreads();
  float m4[4], c4[4];
#pragma unroll
  for (int reg = 0; reg < 4; ++reg) {
    int row = quad * 4 + reg;
    float m = wmax[0][row], c = wcnt0[0][row];
    for (int ww = 1; ww < 8; ++ww) { m = fmaxf(m, wmax[ww][row]); c += wcnt0[ww][row]; }
    m4[reg] = m; c4[reg] = c;
  }

  // ---- round B: exp-sums for pos-path rows (cpos <= 20) ----
  float se4[4] = {0.f, 0.f, 0.f, 0.f};
#pragma unroll
  for (int reg = 0; reg < 4; ++reg) {
    if (c4[reg] <= 20.5f) {
#pragma unroll
      for (int i = 0; i < 16; ++i) {
        float v = V[i][reg];
        if (v > 0.f) se4[reg] += expf(v - m4[reg]);
      }
    }
  }
#pragma unroll
  for (int o = 8; o > 0; o >>= 1)
#pragma unroll
    for (int reg = 0; reg < 4; ++reg) se4[reg] += __shfl_xor(se4[reg], o, 64);
  if (r16 == 0)
#pragma unroll
    for (int reg = 0; reg < 4; ++reg) wexp[w][quad * 4 + reg] = se4[reg];

  // ---- distributed bisection (rows with cpos > 64), lockstep over block ----
  float tlo4[4], thi4[4], tval4[4];
  int done4[4];
#pragma unroll
  for (int reg = 0; reg < 4; ++reg) {
    tval4[reg] = 0.f;
    tlo4[reg] = 0.f; thi4[reg] = m4[reg];
    done4[reg] = (c4[reg] <= 64.5f) ? 1 : 0;
  }
  if (w == 0 && r16 == 0)
#pragma unroll
    for (int reg = 0; reg < 4; ++reg) doneP[quad * 4 + reg] = done4[reg];
  __syncthreads();
  {
    bool ad = true;
    for (int rr = 0; rr < 16; ++rr) if (!doneP[rr]) ad = false;
    if (!ad) {
      for (int it = 0; it < 64; ++it) {
        float mid4[4];
#pragma unroll
        for (int reg = 0; reg < 4; ++reg)
          mid4[reg] = (it < 12)
              ? 0.5f * (tlo4[reg] + thi4[reg])
              : __uint_as_float((__float_as_uint(tlo4[reg]) + __float_as_uint(thi4[reg])) >> 1);
        float cc4[4] = {0.f, 0.f, 0.f, 0.f};
#pragma unroll
        for (int i = 0; i < 16; ++i)
#pragma unroll
          for (int reg = 0; reg < 4; ++reg)
            cc4[reg] += (V[i][reg] > mid4[reg]) ? 1.f : 0.f;
#pragma unroll
        for (int o = 8; o > 0; o >>= 1)
#pragma unroll
          for (int reg = 0; reg < 4; ++reg) cc4[reg] += __shfl_xor(cc4[reg], o, 64);
        if (r16 == 0)
#pragma unroll
          for (int reg = 0; reg < 4; ++reg) wcntB[w][quad * 4 + reg] = cc4[reg];
        __syncthreads();
#pragma unroll
        for (int reg = 0; reg < 4; ++reg) {
          if (!done4[reg]) {
            int row = quad * 4 + reg;
            float c = 0.f;
            for (int ww = 0; ww < 8; ++ww) c += wcntB[ww][row];
            if (c > 64.5f) tlo4[reg] = mid4[reg];
            else if (c < 19.5f) thi4[reg] = mid4[reg];
            else { tval4[reg] = mid4[reg]; done4[reg] = 1; }
            if (it == 63 && !done4[reg]) { tval4[reg] = tlo4[reg]; done4[reg] = 1; }
          }
        }
        if (w == 0 && r16 == 0)
#pragma unroll
          for (int reg = 0; reg < 4; ++reg) doneP[quad * 4 + reg] = done4[reg];
        __syncthreads();
        bool ad2 = true;
        for (int rr = 0; rr < 16; ++rr) if (!doneP[rr]) ad2 = false;
        if (ad2) break;
      }
    }
  }

  // ---- candidate compaction via LDS atomics (ties resolved by sort) ----
  if (tid < 16) candCnt[tid] = 0;
  __syncthreads();
#pragma unroll
  for (int reg = 0; reg < 4; ++reg) {
    if (c4[reg] > 20.5f) {
      int row = quad * 4 + reg;
#pragma unroll
      for (int i = 0; i < 16; ++i) {
        float v = V[i][reg];
        if (v > tval4[reg]) {
          int idx = atomicAdd(&candCnt[row], 1);
          if (idx < 64) {
            candV[row][idx] = v;
            candI[row][idx] = (w + 8 * i) * 16 + r16;
          }
        }
      }
    }
  }
  __syncthreads();

  // ---- per-row params: wave w handles rows 2w, 2w+1 ----
  for (int rr = 0; rr < 2; ++rr) {
    int row = w * 2 + rr;
    float m = wmax[0][row];
    for (int ww = 1; ww < 8; ++ww) m = fmaxf(m, wmax[ww][row]);
    float cpos = 0.f;
    for (int ww = 0; ww < 8; ++ww) cpos += wcnt0[ww][row];
    float em = expf(-m);
    if (cpos <= 20.5f) {
      float s = 0.f;
      for (int ww = 0; ww < 8; ++ww) s += wexp[ww][row];
      float invD = 1.f / (s + (2000.f - cpos) * em);
      if (lane == 0) {
        pthr[row] = __uint_as_float(1u);  // v > 0  <=>  v >= min-denormal
        pm[row] = m; pinv[row] = invD; pdef[row] = em * invD;
      }
    } else {
      int cI = candCnt[row]; if (cI > 64) cI = 64;
      float cv = (lane < cI) ? candV[row][lane] : -1.f;
      int ci = (lane < cI) ? candI[row][lane] : 0x7fffffff;
      // bitonic sort, descending (ties -> lower index first) — same comparator
#pragma unroll
      for (int k = 2; k <= 64; k <<= 1)
#pragma unroll
        for (int j = k >> 1; j > 0; j >>= 1) {
          float ov = __shfl_xor(cv, j, 64);
          int oi = __shfl_xor(ci, j, 64);
          bool otherBetter = (ov > cv) || (ov == cv && oi < ci);
          bool iAmLow = (lane & j) == 0;
          bool desc = (lane & k) == 0;
          bool take = (desc == iAmLow) ? otherBetter : !otherBetter;
          if (take) { cv = ov; ci = oi; }
        }
      float t20 = __shfl(cv, 19, 64);
      float e20 = (lane < 20) ? expf(cv - m) : 0.f;
      float s20 = wredSumAll(e20);
      float invD = 1.f / (s20 + (2000.f - 20.f) * em);
      if (lane == 0) {
        pthr[row] = t20; pm[row] = m; pinv[row] = invD; pdef[row] = em * invD;
      }
    }
  }
  __syncthreads();

  // ---- output: each wave writes its own fragments ----
  float thr4[4], pmm4[4], piv4[4], pdv4[4];
#pragma unroll
  for (int reg = 0; reg < 4; ++reg) {
    int row = quad * 4 + reg;
    thr4[reg] = pthr[row]; pmm4[reg] = pm[row];
    piv4[reg] = pinv[row]; pdv4[reg] = pdef[row];
  }
  const size_t ob0 = ((size_t)(b * NN + n0)) * NN;
#pragma unroll
  for (int i = 0; i < 16; ++i) {
    int tl = w + 8 * i;
    if (tl > 124) continue;
    int mcol = tl * 16 + r16;
#pragma unroll
    for (int reg = 0; reg < 4; ++reg) {
      int row = quad * 4 + reg;
      float v = V[i][reg];
      float o = (v >= thr4[reg]) ? expf(v - pmm4[reg]) * piv4[reg] : pdv4[reg];
      out[ob0 + (size_t)row * NN + mcol] = o;
    }
  }
}

extern "C" void kernel_launch(void* const* d_in, const int* in_sizes, int n_in,
                              void* d_out, int out_size, void* d_ws, size_t ws_size,
                              hipStream_t stream) {
  const float* x     = (const float*)d_in[0];
  const float* Ex    = (const float*)d_in[1];
  const float* nodes = (const float*)d_in[2];
  const float* Wd    = (const float*)d_in[3];
  const float* Wx    = (const float*)d_in[4];
  float* out = (float*)d_out;
  float* w = (float*)d_ws;
  float* tw  = w + OFF_TW;
  float* xf  = w + OFF_XF;
  float* icn = w + OFF_ICN;
  float* irn = w + OFF_IRN;
  float* xe  = w + OFF_XE;
  float* x1  = w + OFF_X1;
  float* csw = w + OFF_CSW;
  float* lns = w + OFF_LNS;
  ushort_t* adphl = (ushort_t*)(w + OFF_ADP);
  ushort_t* x1hl  = (ushort_t*)(w + OFF_XE);  // reuses dead xe region

  k_tw<<<(TT * FLEN + 255) / 256, 256, 0, stream>>>(Wx, tw, csw, lns);
  k_dft<<<dim3(16, 5, BB), 256, 0, stream>>>(x, tw, xf);
  k_colnorm<<<BB * FLEN, 256, 0, stream>>>(xf, icn);
  k_rownorm<<<dim3(8, BB), 256, 0, stream>>>(xf, icn, irn);
  k_xe<<<dim3(32, BB), 256, 0, stream>>>(xf, icn, irn, Ex, xe);
  k_x1<<<NN, 256, 0, stream>>>(xe, nodes, Wd, x1, x1hl);
  k_ln_stats<<<dim3(32, BB), 256, 0, stream>>>(x1, lns);
  k_adp<<<250, 256, 0, stream>>>(x1, Wx, csw, lns, adphl);
  k_adjsm<<<dim3(125, BB), 512, 0, stream>>>(adphl, x1hl, out);
}

// Round 9
// 487.634 us; speedup vs baseline: 1.0978x; 1.0978x over previous
//
#include <hip/hip_runtime.h>
#include <math.h>

#define BB 8
#define TT 288
#define NN 2000
#define FLEN 145
#define EE 128
#define IDD 16
#define HH 128
#define DKK 144
#define KTOP 20

typedef _Float16 half8 __attribute__((ext_vector_type(8)));
typedef float f32x4 __attribute__((ext_vector_type(4)));
typedef unsigned short ushort_t;

// ---- workspace layout (float offsets) ----
#define OFF_TW  ((size_t)0)
#define SZ_TW   ((size_t)TT*FLEN*2)
#define OFF_XF  (OFF_TW + SZ_TW)
#define SZ_XF   ((size_t)BB*FLEN*NN)
#define OFF_ICN (OFF_XF + SZ_XF)
#define OFF_IRN (OFF_ICN + (size_t)BB*FLEN)
#define OFF_XE  (OFF_IRN + (size_t)BB*NN)   // after k_x1 consumes xe, region is reused as x1 hi/lo fp16 (fragment-tiled)
#define SZ_BNH  ((size_t)BB*NN*HH)
#define OFF_X1  (OFF_XE + SZ_BNH)
#define OFF_ADP (OFF_X1 + SZ_BNH)           // holds adp hi/lo fp16 (fragment-tiled), never fp32
#define OFF_CSW (OFF_ADP + SZ_BNH)
#define OFF_LNS (OFF_CSW + HH)
#define OFF_LNF (OFF_LNS + 16)

// Fragment-tiled hi/lo layout (NN = 125*16 exactly):
//   ushort offset = (b*125 + (n>>4))*4096 + hl*2048 + (k>>5)*512
//                 + ((k>>3)&3)*128 + (n&15)*8 + (k&7)
// A wave's MFMA fragment load (lane = quad*16+r16) is ONE contiguous 1KB read.
// (The old per-row layout was a 16-segment 64B gather per load -> 16x
// transaction amplification; fixing it took k_adjT 140 -> ~60 us.)

__device__ __forceinline__ float wredSum(float v) {
#pragma unroll
  for (int o = 32; o > 0; o >>= 1) v += __shfl_down(v, o, 64);
  return v;
}
// butterfly variants: result valid in ALL lanes
__device__ __forceinline__ float wredSumAll(float v) {
#pragma unroll
  for (int o = 32; o > 0; o >>= 1) v += __shfl_xor(v, o, 64);
  return v;
}
__device__ __forceinline__ float wredMaxAll(float v) {
#pragma unroll
  for (int o = 32; o > 0; o >>= 1) v = fmaxf(v, __shfl_xor(v, o, 64));
  return v;
}

// fp16 hi/lo split: v = hi + lo + O(2^-22 * v)
__device__ __forceinline__ void split16(float v, ushort_t& hi, ushort_t& lo) {
  _Float16 h = (_Float16)v;
  _Float16 l = (_Float16)(v - (float)h);
  union { _Float16 f; ushort_t u; } a, b;
  a.f = h; b.f = l;
  hi = a.u; lo = b.u;
}

// twiddles (exact int reduction of angle) + merged init work in block 0
__global__ void k_tw(const float* __restrict__ Wx, float* __restrict__ tw,
                     float* __restrict__ csw, float* __restrict__ lns) {
  if (blockIdx.x == 0 && threadIdx.x < 128) {
    int k = threadIdx.x;
    float s = 0.f;
    for (int h = 0; h < HH; ++h) s += Wx[h * HH + k];
    csw[k] = s;
    if (k < 16) lns[k] = 0.f;
  }
  int id = blockIdx.x * 256 + threadIdx.x;
  if (id >= TT * FLEN) return;
  int t = id / FLEN, f = id % FLEN;
  int r = (t * f) % TT;
  double th = -2.0 * 3.14159265358979323846 * (double)r / (double)TT;
  tw[2 * id]     = (float)cos(th);
  tw[2 * id + 1] = (float)sin(th);
}

// xf[b][f][n] = |rfft(x[b,:,n])[f]|
__global__ void k_dft(const float* __restrict__ x, const float* __restrict__ tw,
                      float* __restrict__ xf) {
  __shared__ __align__(16) float Xs[16][128];
  __shared__ __align__(16) float TWs[16][32][2];
  const int b = blockIdx.z;
  const int f0 = blockIdx.y * 32;
  const int n0 = blockIdx.x * 128;
  const int tid = threadIdx.x;
  const int tn = tid & 31;
  const int tf = tid >> 5;
  float ar[4][4] = {}, ai[4][4] = {};
  for (int t0 = 0; t0 < TT; t0 += 16) {
    __syncthreads();
    for (int l = tid; l < 512; l += 256) {
      int row = l >> 5, q = l & 31;
      int n = n0 + q * 4;
      const float* src = x + ((size_t)b * TT + (t0 + row)) * NN + n;
      float4 v = make_float4(0, 0, 0, 0);
      if (n + 3 < NN) v = *(const float4*)src;
      else {
        if (n + 0 < NN) v.x = src[0];
        if (n + 1 < NN) v.y = src[1];
        if (n + 2 < NN) v.z = src[2];
        if (n + 3 < NN) v.w = src[3];
      }
      *(float4*)&Xs[row][q * 4] = v;
    }
    for (int l = tid; l < 512; l += 256) {
      int row = l >> 5, ff = l & 31;
      int f = f0 + ff;
      float2 cs = make_float2(0, 0);
      if (f < FLEN) cs = *(const float2*)&tw[((size_t)(t0 + row) * FLEN + f) * 2];
      *(float2*)&TWs[row][ff][0] = cs;
    }
    __syncthreads();
#pragma unroll 4
    for (int t = 0; t < 16; ++t) {
      float4 xv = *(float4*)&Xs[t][tn * 4];
      float xx[4] = {xv.x, xv.y, xv.z, xv.w};
      float4 p0 = *(float4*)&TWs[t][tf * 4][0];
      float4 p1 = *(float4*)&TWs[t][tf * 4 + 2][0];
      float c[4] = {p0.x, p0.z, p1.x, p1.z};
      float s[4] = {p0.y, p0.w, p1.y, p1.w};
#pragma unroll
      for (int i = 0; i < 4; ++i)
#pragma unroll
        for (int j = 0; j < 4; ++j) {
          ar[i][j] = fmaf(xx[j], c[i], ar[i][j]);
          ai[i][j] = fmaf(xx[j], s[i], ai[i][j]);
        }
    }
  }
#pragma unroll
  for (int i = 0; i < 4; ++i) {
    int f = f0 + tf * 4 + i;
    if (f >= FLEN) continue;
    float* dst = &xf[((size_t)b * FLEN + f) * NN];
    float o[4];
#pragma unroll
    for (int j = 0; j < 4; ++j)
      o[j] = sqrtf(ar[i][j] * ar[i][j] + ai[i][j] * ai[i][j]);
    int n = n0 + tn * 4;
    if (n + 3 < NN) *(float4*)&dst[n] = make_float4(o[0], o[1], o[2], o[3]);
    else {
#pragma unroll
      for (int j = 0; j < 4; ++j) if (n + j < NN) dst[n + j] = o[j];
    }
  }
}

__global__ void k_colnorm(const float* __restrict__ xf, float* __restrict__ icn) {
  __shared__ float sc[4];
  int bf = blockIdx.x;
  const float* rowp = xf + (size_t)bf * NN;
  float s = 0.f;
  for (int i = threadIdx.x; i < NN; i += 256) { float v = rowp[i]; s = fmaf(v, v, s); }
  s = wredSum(s);
  int lane = threadIdx.x & 63, w = threadIdx.x >> 6;
  if (lane == 0) sc[w] = s;
  __syncthreads();
  if (threadIdx.x == 0)
    icn[bf] = 1.f / fmaxf(sqrtf(sc[0] + sc[1] + sc[2] + sc[3]), 1e-12f);
}

__global__ void k_rownorm(const float* __restrict__ xf, const float* __restrict__ icn,
                          float* __restrict__ irn) {
  int b = blockIdx.y;
  int n = blockIdx.x * 256 + threadIdx.x;
  if (n >= NN) return;
  float s = 0.f;
  for (int f = 0; f < FLEN; ++f) {
    float v = xf[((size_t)b * FLEN + f) * NN + n] * icn[b * FLEN + f];
    s = fmaf(v, v, s);
  }
  irn[b * NN + n] = 1.f / fmaxf(sqrtf(s), 1e-12f);
}

__global__ void k_xe(const float* __restrict__ xf, const float* __restrict__ icn,
                     const float* __restrict__ irn, const float* __restrict__ Ex,
                     float* __restrict__ xe) {
  __shared__ __align__(16) float As[16][64];
  __shared__ __align__(16) float Bs[16][128];
  const int b = blockIdx.y;
  const int n0 = blockIdx.x * 64;
  const int tid = threadIdx.x;
  const int tn = tid >> 4, te = tid & 15;
  float acc[4][8] = {};
  for (int f0 = 0; f0 < 160; f0 += 16) {
    __syncthreads();
    {
      int kt = tid >> 4, q = tid & 15;
      int f = f0 + kt;
      int n = n0 + q * 4;
      float4 v = make_float4(0, 0, 0, 0);
      if (f < FLEN) {
        float ic = icn[b * FLEN + f];
        const float* src = &xf[((size_t)b * FLEN + f) * NN + n];
        if (n + 3 < NN) v = *(const float4*)src;
        else {
          if (n + 0 < NN) v.x = src[0];
          if (n + 1 < NN) v.y = src[1];
          if (n + 2 < NN) v.z = src[2];
          if (n + 3 < NN) v.w = src[3];
        }
        v.x *= ic; v.y *= ic; v.z *= ic; v.w *= ic;
      }
      *(float4*)&As[kt][q * 4] = v;
    }
    for (int l = tid; l < 512; l += 256) {
      int kt = l >> 5, q = l & 31;
      int f = f0 + kt;
      float4 v = make_float4(0, 0, 0, 0);
      if (f < FLEN) v = *(const float4*)&Ex[(size_t)f * EE + q * 4];
      *(float4*)&Bs[kt][q * 4] = v;
    }
    __syncthreads();
#pragma unroll
    for (int k = 0; k < 16; ++k) {
      float4 a  = *(float4*)&As[k][tn * 4];
      float4 b0 = *(float4*)&Bs[k][te * 4];
      float4 b1 = *(float4*)&Bs[k][64 + te * 4];
      float av[4] = {a.x, a.y, a.z, a.w};
      float bv[8] = {b0.x, b0.y, b0.z, b0.w, b1.x, b1.y, b1.z, b1.w};
#pragma unroll
      for (int i = 0; i < 4; ++i)
#pragma unroll
        for (int j = 0; j < 8; ++j)
          acc[i][j] = fmaf(av[i], bv[j], acc[i][j]);
    }
  }
#pragma unroll
  for (int i = 0; i < 4; ++i) {
    int n = n0 + tn * 4 + i;
    if (n >= NN) continue;
    float sc = irn[b * NN + n];
    float* dst = &xe[((size_t)b * NN + n) * EE];
    *(float4*)&dst[te * 4] =
        make_float4(acc[i][0] * sc, acc[i][1] * sc, acc[i][2] * sc, acc[i][3] * sc);
    *(float4*)&dst[64 + te * 4] =
        make_float4(acc[i][4] * sc, acc[i][5] * sc, acc[i][6] * sc, acc[i][7] * sc);
  }
}

// x1 = relu([xe|nodes] . Wd[n]); emits x1 hi/lo fp16 fragment-tiled into dead xe region.
__global__ void k_x1(const float* xe, const float* __restrict__ nodes,
                     const float* __restrict__ Wd, float* __restrict__ x1,
                     ushort_t* x1hl) {
  __shared__ __align__(16) float xk[8][DKK];
  __shared__ float red[4][32][33];
  const int n = blockIdx.x;
  const int tid = threadIdx.x;
  {
    int b = tid >> 5, q = tid & 31;
    *(float4*)&xk[b][q * 4] = *(const float4*)&xe[((size_t)b * NN + n) * EE + q * 4];
  }
  if (tid < 128) {
    int b = tid >> 4, i = tid & 15;
    xk[b][EE + i] = nodes[(size_t)n * IDD + i];
  }
  __syncthreads();
  const int h4 = tid & 31;
  const int dg = tid >> 5;
  float acc[8][4] = {};
  for (int d = dg; d < DKK; d += 8) {
    float4 wv = *(const float4*)&Wd[((size_t)n * DKK + d) * HH + h4 * 4];
#pragma unroll
    for (int b = 0; b < 8; ++b) {
      float xv = xk[b][d];
      acc[b][0] = fmaf(xv, wv.x, acc[b][0]);
      acc[b][1] = fmaf(xv, wv.y, acc[b][1]);
      acc[b][2] = fmaf(xv, wv.z, acc[b][2]);
      acc[b][3] = fmaf(xv, wv.w, acc[b][3]);
    }
  }
#pragma unroll
  for (int b = 0; b < 8; ++b)
#pragma unroll
    for (int j = 0; j < 4; ++j)
      acc[b][j] += __shfl_xor(acc[b][j], 32, 64);
  const int wv_ = tid >> 6, lane = tid & 63;
  if (lane < 32) {
#pragma unroll
    for (int b = 0; b < 8; ++b)
#pragma unroll
      for (int j = 0; j < 4; ++j)
        red[wv_][lane][b * 4 + j] = acc[b][j];
  }
  __syncthreads();
  const size_t tbase = (size_t)(n >> 4) * 4096 + (size_t)(n & 15) * 8;
#pragma unroll
  for (int o = 0; o < 4; ++o) {
    int idx = tid + o * 256;
    int b = idx >> 7, h = idx & 127;
    float s = red[0][h >> 2][b * 4 + (h & 3)] + red[1][h >> 2][b * 4 + (h & 3)] +
              red[2][h >> 2][b * 4 + (h & 3)] + red[3][h >> 2][b * 4 + (h & 3)];
    s = fmaxf(s, 0.f);
    x1[((size_t)b * NN + n) * HH + h] = s;
    ushort_t hi, lo;
    split16(s, hi, lo);
    size_t slot = (size_t)b * (125 * 4096) + tbase +
                  (size_t)((h >> 5) * 512 + ((h >> 3) & 3) * 128 + (h & 7));
    x1hl[slot] = hi;
    x1hl[slot + 2048] = lo;
  }
}

__global__ void k_ln_stats(const float* __restrict__ x1, float* __restrict__ lns) {
  __shared__ float sc[4], sc2[4];
  int b = blockIdx.y, chunk = blockIdx.x;
  const float* base = x1 + (size_t)b * NN * HH + (size_t)chunk * 8000;
  float s = 0.f, s2 = 0.f;
  for (int i = threadIdx.x; i < 8000; i += 256) {
    float v = base[i];
    s += v; s2 = fmaf(v, v, s2);
  }
  s = wredSum(s); s2 = wredSum(s2);
  int lane = threadIdx.x & 63, w = threadIdx.x >> 6;
  if (lane == 0) { sc[w] = s; sc2[w] = s2; }
  __syncthreads();
  if (threadIdx.x == 0) {
    atomicAdd(&lns[b], sc[0] + sc[1] + sc[2] + sc[3]);
    atomicAdd(&lns[8 + b], sc2[0] + sc2[1] + sc2[2] + sc2[3]);
  }
}

// adp = ((x1 . Wx) - mu*colsumW) * inv_sd, fp16 hi/lo fragment-tiled.
// LN-final (mu/isd from raw sums) inlined -- bit-identical arithmetic.
__global__ void k_adp(const float* __restrict__ x1, const float* __restrict__ Wx,
                      const float* __restrict__ csw, const float* __restrict__ lns,
                      ushort_t* __restrict__ adphl) {
  __shared__ __align__(16) float As[16][64];
  __shared__ __align__(16) float Bs[16][128];
  const int r0 = blockIdx.x * 64;
  const int tid = threadIdx.x;
  const int tn = tid >> 4, te = tid & 15;
  float acc[4][8] = {};
  for (int k0 = 0; k0 < HH; k0 += 16) {
    __syncthreads();
    {
      int rr = tid >> 2, kq = tid & 3;
      float4 v = *(const float4*)&x1[(size_t)(r0 + rr) * HH + k0 + kq * 4];
      As[kq * 4 + 0][rr] = v.x;
      As[kq * 4 + 1][rr] = v.y;
      As[kq * 4 + 2][rr] = v.z;
      As[kq * 4 + 3][rr] = v.w;
    }
    for (int l = tid; l < 512; l += 256) {
      int kt = l >> 5, q = l & 31;
      *(float4*)&Bs[kt][q * 4] = *(const float4*)&Wx[(size_t)(k0 + kt) * HH + q * 4];
    }
    __syncthreads();
#pragma unroll
    for (int k = 0; k < 16; ++k) {
      float4 a  = *(float4*)&As[k][tn * 4];
      float4 b0 = *(float4*)&Bs[k][te * 4];
      float4 b1 = *(float4*)&Bs[k][64 + te * 4];
      float av[4] = {a.x, a.y, a.z, a.w};
      float bv[8] = {b0.x, b0.y, b0.z, b0.w, b1.x, b1.y, b1.z, b1.w};
#pragma unroll
      for (int i = 0; i < 4; ++i)
#pragma unroll
        for (int j = 0; j < 8; ++j)
          acc[i][j] = fmaf(av[i], bv[j], acc[i][j]);
    }
  }
  float4 c0 = *(const float4*)&csw[te * 4];
  float4 c1 = *(const float4*)&csw[64 + te * 4];
  float cw[8] = {c0.x, c0.y, c0.z, c0.w, c1.x, c1.y, c1.z, c1.w};
  const int c0k = te * 4, c1k = 64 + te * 4;
  const size_t o0r = (size_t)((c0k >> 5) * 512 + ((c0k >> 3) & 3) * 128 + (c0k & 7));
  const size_t o1r = (size_t)((c1k >> 5) * 512 + ((c1k >> 3) & 3) * 128 + (c1k & 7));
#pragma unroll
  for (int i = 0; i < 4; ++i) {
    int r = r0 + tn * 4 + i;
    int b = r / NN, n = r % NN;
    float cnt = (float)(NN * HH);
    float mu = lns[b] / cnt;
    float var = fmaxf(lns[8 + b] / cnt - mu * mu, 0.f);
    float isd = 1.f / sqrtf(var + 1e-8f);
    ushort_t hi[8], lo[8];
#pragma unroll
    for (int j = 0; j < 8; ++j) {
      float o = (acc[i][j] - mu * cw[j]) * isd;
      split16(o, hi[j], lo[j]);
    }
    size_t slot = (size_t)b * (125 * 4096) + (size_t)(n >> 4) * 4096 +
                  (size_t)(n & 15) * 8;
    ushort4 u;
    u.x = hi[0]; u.y = hi[1]; u.z = hi[2]; u.w = hi[3];
    *(ushort4*)&adphl[slot + o0r] = u;
    u.x = hi[4]; u.y = hi[5]; u.z = hi[6]; u.w = hi[7];
    *(ushort4*)&adphl[slot + o1r] = u;
    u.x = lo[0]; u.y = lo[1]; u.z = lo[2]; u.w = lo[3];
    *(ushort4*)&adphl[slot + 2048 + o0r] = u;
    u.x = lo[4]; u.y = lo[5]; u.z = lo[6]; u.w = lo[7];
    *(ushort4*)&adphl[slot + 2048 + o1r] = u;
  }
}

// ================= adj GEMM -> relu -> out (fp32, in place in d_out) ==========
// Fragment-tiled operands: every A/B fragment load is ONE contiguous 1KB
// instruction. Register-double-buffered B with sched_barrier(0) pinning the
// prefetch. (Proven ~60us in round 6; fusion attempts with topk all regressed
// on VGPR/occupancy ceilings -- see rounds 0,1,7.)
__global__ __launch_bounds__(256, 2) void k_adjT(
    const ushort_t* __restrict__ adphl, const ushort_t* __restrict__ x1hl,
    float* __restrict__ out) {
  const int b = blockIdx.z;
  const int tA = blockIdx.y;          // n-tile 0..124
  const int n0 = tA * 16;
  const int tid = threadIdx.x;
  const int w = tid >> 6;
  const int lane = tid & 63;
  const int quad = lane >> 4, r16 = lane & 15;
  const int lq = quad * 128 + r16 * 8;  // fragment lane offset (ushorts)

  half8 Ah[4], Al[4];
  {
    const ushort_t* abase = adphl + ((size_t)(b * 125 + tA)) * 4096 + lq;
#pragma unroll
    for (int ks = 0; ks < 4; ++ks) {
      Ah[ks] = *(const half8*)(abase + ks * 512);
      Al[ks] = *(const half8*)(abase + 2048 + ks * 512);
    }
  }
  const int mbase = blockIdx.x * 512 + w * 128;  // 8 subtiles of 16
  const ushort_t* Bb = x1hl + (size_t)b * (125 * 4096) + lq;
  float* obase = out + ((size_t)(b * NN + n0 + quad * 4)) * NN;

  half8 Bh0[4], Bl0[4], Bh1[4], Bl1[4];

#define LOADB(I, BH, BL)                                                      \
  {                                                                           \
    int tB_ = (mbase + (I) * 16) >> 4;                                        \
    if (tB_ > 124) tB_ = 124; /* m-subtiles >=2000 are store-masked */        \
    const ushort_t* bb_ = Bb + (size_t)tB_ * 4096;                            \
    BH[0] = *(const half8*)(bb_);        BL[0] = *(const half8*)(bb_ + 2048); \
    BH[1] = *(const half8*)(bb_ + 512);  BL[1] = *(const half8*)(bb_ + 2560); \
    BH[2] = *(const half8*)(bb_ + 1024); BL[2] = *(const half8*)(bb_ + 3072); \
    BH[3] = *(const half8*)(bb_ + 1536); BL[3] = *(const half8*)(bb_ + 3584); \
  }

#define STEP(I, BH, BL, BH2, BL2)                                             \
  {                                                                           \
    if ((I) < 7) LOADB((I) + 1, BH2, BL2);                                    \
    __builtin_amdgcn_sched_barrier(0); /* pin prefetch above the MFMAs */     \
    f32x4 acc = (f32x4){0.f, 0.f, 0.f, 0.f};                                  \
    _Pragma("unroll")                                                         \
    for (int ks = 0; ks < 4; ++ks) {                                          \
      acc = __builtin_amdgcn_mfma_f32_16x16x32_f16(Ah[ks], BH[ks], acc, 0, 0, 0); \
      acc = __builtin_amdgcn_mfma_f32_16x16x32_f16(Ah[ks], BL[ks], acc, 0, 0, 0); \
      acc = __builtin_amdgcn_mfma_f32_16x16x32_f16(Al[ks], BH[ks], acc, 0, 0, 0); \
    }                                                                         \
    int mt_ = mbase + (I) * 16 + r16;                                         \
    if (mt_ < NN) {                                                           \
      _Pragma("unroll")                                                       \
      for (int reg = 0; reg < 4; ++reg)                                       \
        obase[(size_t)reg * NN + mt_] = fmaxf(acc[reg], 0.f);                 \
    }                                                                         \
  }

  LOADB(0, Bh0, Bl0);
  STEP(0, Bh0, Bl0, Bh1, Bl1);
  STEP(1, Bh1, Bl1, Bh0, Bl0);
  STEP(2, Bh0, Bl0, Bh1, Bl1);
  STEP(3, Bh1, Bl1, Bh0, Bl0);
  STEP(4, Bh0, Bl0, Bh1, Bl1);
  STEP(5, Bh1, Bl1, Bh0, Bl0);
  STEP(6, Bh0, Bl0, Bh1, Bl1);
  STEP(7, Bh1, Bl1, Bh0, Bl0);
#undef STEP
#undef LOADB
}

// ================= per-row topk-mask + softmax, in place on d_out =============
// One wave per row, 4 waves/block, 16000 independent waves; row lives in
// registers (V[8] f32x4). topk-20: positive-count -> threshold bisection into
// [20,64] candidates -> ballot-compact to per-wave LDS -> 64-wide bitonic
// sort -> t20 = rank-19 value. No block barriers.
__global__ __launch_bounds__(256, 4) void k_topsm(float* out) {
  __shared__ float scrV[4][64];
  __shared__ int scrI[4][64];
  const int tid = threadIdx.x;
  const int w = tid >> 6, lane = tid & 63;
  const int r = blockIdx.x * 4 + w;  // 0..15999
  float* g = out + (size_t)r * NN;

  f32x4 V[8];  // lane's 32 values: m = j*256 + lane*4 + e
#pragma unroll
  for (int j = 0; j < 8; ++j) {
    int m0 = j * 256 + lane * 4;
    if (m0 < NN) V[j] = *(const f32x4*)&g[m0];
    else V[j] = (f32x4){-1.f, -1.f, -1.f, -1.f};
  }

  float mx = -1.f, cp = 0.f;
#pragma unroll
  for (int j = 0; j < 8; ++j)
#pragma unroll
    for (int e = 0; e < 4; ++e) {
      mx = fmaxf(mx, V[j][e]);
      cp += (V[j][e] > 0.f) ? 1.f : 0.f;
    }
  const float m = wredMaxAll(mx);  // >= 0 (relu)
  const float cpos = wredSumAll(cp);
  const float em = expf(-m);

  if (cpos <= 20.5f) {
    // all positives are in the top-20; zero-ties give identical output
    float s = 0.f;
#pragma unroll
    for (int j = 0; j < 8; ++j)
#pragma unroll
      for (int e = 0; e < 4; ++e)
        if (V[j][e] > 0.f) s += expf(V[j][e] - m);
    s = wredSumAll(s);
    const float invD = 1.f / (s + (2000.f - cpos) * em);
    const float defv = em * invD;
#pragma unroll
    for (int j = 0; j < 8; ++j) {
      int m0 = j * 256 + lane * 4;
      if (m0 >= NN) continue;
      float4 o;
      o.x = (V[j][0] > 0.f) ? expf(V[j][0] - m) * invD : defv;
      o.y = (V[j][1] > 0.f) ? expf(V[j][1] - m) * invD : defv;
      o.z = (V[j][2] > 0.f) ? expf(V[j][2] - m) * invD : defv;
      o.w = (V[j][3] > 0.f) ? expf(V[j][3] - m) * invD : defv;
      *(float4*)&g[m0] = o;
    }
  } else {
    // bracket candidate count into [20,64]
    float tval = 0.f, cf = cpos;
    if (cpos > 64.5f) {
      float tlo = 0.f, thi = m;
      bool found = false;
      for (int it = 0; it < 64 && !found; ++it) {
        float mid = (it < 12)
            ? 0.5f * (tlo + thi)
            : __uint_as_float((__float_as_uint(tlo) + __float_as_uint(thi)) >> 1);
        float c = 0.f;
#pragma unroll
        for (int j = 0; j < 8; ++j)
#pragma unroll
          for (int e = 0; e < 4; ++e)
            c += (V[j][e] > mid) ? 1.f : 0.f;
        c = wredSumAll(c);
        if (c > 64.5f) tlo = mid;
        else if (c < 19.5f) thi = mid;
        else { tval = mid; cf = c; found = true; }
      }
      if (!found) { tval = tlo; cf = 64.f; }  // unreachable for distinct floats
    }
    int cI = (int)(cf + 0.5f);
    if (cI > 64) cI = 64;

    // ballot-compact candidates {v > tval} into per-wave LDS scratch
    float* sv = scrV[w];
    int* si = scrI[w];
    int base = 0;
#pragma unroll
    for (int j = 0; j < 8; ++j)
#pragma unroll
      for (int e = 0; e < 4; ++e) {
        bool p = V[j][e] > tval;
        unsigned long long msk = __ballot(p);
        if (p) {
          int pos = base + (int)__popcll(msk & ((1ull << lane) - 1ull));
          if (pos < 64) { sv[pos] = V[j][e]; si[pos] = j * 256 + lane * 4 + e; }
        }
        base += (int)__popcll(msk);
      }
    asm volatile("s_waitcnt lgkmcnt(0)" ::: "memory");

    float cv = (lane < cI) ? sv[lane] : -1.f;
    int ci = (lane < cI) ? si[lane] : 0x7fffffff;
    // bitonic sort, descending (ties -> lower index first)
#pragma unroll
    for (int k = 2; k <= 64; k <<= 1)
#pragma unroll
      for (int j = k >> 1; j > 0; j >>= 1) {
        float ov = __shfl_xor(cv, j, 64);
        int oi = __shfl_xor(ci, j, 64);
        bool otherBetter = (ov > cv) || (ov == cv && oi < ci);
        bool iAmLow = (lane & j) == 0;
        bool desc = (lane & k) == 0;
        bool take = (desc == iAmLow) ? otherBetter : !otherBetter;
        if (take) { cv = ov; ci = oi; }
      }
    const float t20 = __shfl(cv, 19, 64);  // 20th largest (cI >= 20)
    float e20 = (lane < 20) ? expf(cv - m) : 0.f;
    const float s20 = wredSumAll(e20);
    const float invD = 1.f / (s20 + (2000.f - 20.f) * em);
    const float defv = em * invD;
#pragma unroll
    for (int j = 0; j < 8; ++j) {
      int m0 = j * 256 + lane * 4;
      if (m0 >= NN) continue;
      float4 o;
      o.x = (V[j][0] >= t20) ? expf(V[j][0] - m) * invD : defv;
      o.y = (V[j][1] >= t20) ? expf(V[j][1] - m) * invD : defv;
      o.z = (V[j][2] >= t20) ? expf(V[j][2] - m) * invD : defv;
      o.w = (V[j][3] >= t20) ? expf(V[j][3] - m) * invD : defv;
      *(float4*)&g[m0] = o;
    }
  }
}

extern "C" void kernel_launch(void* const* d_in, const int* in_sizes, int n_in,
                              void* d_out, int out_size, void* d_ws, size_t ws_size,
                              hipStream_t stream) {
  const float* x     = (const float*)d_in[0];
  const float* Ex    = (const float*)d_in[1];
  const float* nodes = (const float*)d_in[2];
  const float* Wd    = (const float*)d_in[3];
  const float* Wx    = (const float*)d_in[4];
  float* out = (float*)d_out;
  float* w = (float*)d_ws;
  float* tw  = w + OFF_TW;
  float* xf  = w + OFF_XF;
  float* icn = w + OFF_ICN;
  float* irn = w + OFF_IRN;
  float* xe  = w + OFF_XE;
  float* x1  = w + OFF_X1;
  float* csw = w + OFF_CSW;
  float* lns = w + OFF_LNS;
  ushort_t* adphl = (ushort_t*)(w + OFF_ADP);
  ushort_t* x1hl  = (ushort_t*)(w + OFF_XE);  // reuses dead xe region

  k_tw<<<(TT * FLEN + 255) / 256, 256, 0, stream>>>(Wx, tw, csw, lns);
  k_dft<<<dim3(16, 5, BB), 256, 0, stream>>>(x, tw, xf);
  k_colnorm<<<BB * FLEN, 256, 0, stream>>>(xf, icn);
  k_rownorm<<<dim3(8, BB), 256, 0, stream>>>(xf, icn, irn);
  k_xe<<<dim3(32, BB), 256, 0, stream>>>(xf, icn, irn, Ex, xe);
  k_x1<<<NN, 256, 0, stream>>>(xe, nodes, Wd, x1, x1hl);
  k_ln_stats<<<dim3(32, BB), 256, 0, stream>>>(x1, lns);
  k_adp<<<250, 256, 0, stream>>>(x1, Wx, csw, lns, adphl);
  k_adjT<<<dim3(4, 125, BB), 256, 0, stream>>>(adphl, x1hl, out);
  k_topsm<<<(BB * NN) / 4, 256, 0, stream>>>(out);
}

// Round 11
// 482.078 us; speedup vs baseline: 1.1105x; 1.0115x over previous
//
#include <hip/hip_runtime.h>
#include <math.h>

#define BB 8
#define TT 288
#define NN 2000
#define FLEN 145
#define EE 128
#define IDD 16
#define HH 128
#define DKK 144
#define KTOP 20

typedef _Float16 half8 __attribute__((ext_vector_type(8)));
typedef float f32x4 __attribute__((ext_vector_type(4)));
typedef unsigned short ushort_t;

// ---- workspace layout (float offsets) ----
#define OFF_TW  ((size_t)0)
#define SZ_TW   ((size_t)TT*FLEN*2)
#define OFF_XF  (OFF_TW + SZ_TW)
#define SZ_XF   ((size_t)BB*FLEN*NN)
#define OFF_ICN (OFF_XF + SZ_XF)
#define OFF_IRN (OFF_ICN + (size_t)BB*FLEN)   // irn now computed inside k_xe; slot kept for layout stability
#define OFF_XE  (OFF_IRN + (size_t)BB*NN)     // after k_x1 consumes xe, region is reused as x1 hi/lo fp16 (fragment-tiled)
#define SZ_BNH  ((size_t)BB*NN*HH)
#define OFF_X1  (OFF_XE + SZ_BNH)
#define OFF_ADP (OFF_X1 + SZ_BNH)             // holds adp hi/lo fp16 (fragment-tiled), never fp32
#define OFF_CSW (OFF_ADP + SZ_BNH)
#define OFF_LNS (OFF_CSW + HH)
#define OFF_LNF (OFF_LNS + 16)

// Fragment-tiled hi/lo layout (NN = 125*16 exactly):
//   ushort offset = (b*125 + (n>>4))*4096 + hl*2048 + (k>>5)*512
//                 + ((k>>3)&3)*128 + (n&15)*8 + (k&7)
// A wave's MFMA fragment load (lane = quad*16+r16) is ONE contiguous 1KB read.

__device__ __forceinline__ float wredSum(float v) {
#pragma unroll
  for (int o = 32; o > 0; o >>= 1) v += __shfl_down(v, o, 64);
  return v;
}
// butterfly variants: result valid in ALL lanes
__device__ __forceinline__ float wredSumAll(float v) {
#pragma unroll
  for (int o = 32; o > 0; o >>= 1) v += __shfl_xor(v, o, 64);
  return v;
}
__device__ __forceinline__ float wredMaxAll(float v) {
#pragma unroll
  for (int o = 32; o > 0; o >>= 1) v = fmaxf(v, __shfl_xor(v, o, 64));
  return v;
}

// fp16 hi/lo split: v = hi + lo + O(2^-22 * v)
__device__ __forceinline__ void split16(float v, ushort_t& hi, ushort_t& lo) {
  _Float16 h = (_Float16)v;
  _Float16 l = (_Float16)(v - (float)h);
  union { _Float16 f; ushort_t u; } a, b;
  a.f = h; b.f = l;
  hi = a.u; lo = b.u;
}

// twiddles (exact int reduction of angle) + merged init work in block 0
__global__ void k_tw(const float* __restrict__ Wx, float* __restrict__ tw,
                     float* __restrict__ csw, float* __restrict__ lns) {
  if (blockIdx.x == 0 && threadIdx.x < 128) {
    int k = threadIdx.x;
    float s = 0.f;
    for (int h = 0; h < HH; ++h) s += Wx[h * HH + k];
    csw[k] = s;
    if (k < 16) lns[k] = 0.f;
  }
  int id = blockIdx.x * 256 + threadIdx.x;
  if (id >= TT * FLEN) return;
  int t = id / FLEN, f = id % FLEN;
  int r = (t * f) % TT;
  double th = -2.0 * 3.14159265358979323846 * (double)r / (double)TT;
  tw[2 * id]     = (float)cos(th);
  tw[2 * id + 1] = (float)sin(th);
}

// xf[b][f][n] = |rfft(x[b,:,n])[f]|
// 4f x 8n per thread (was 4x4): halves LDS-reads per fma. Per-(f,n) fma chain
// order is UNCHANGED (t ascending) -> bit-identical xf.
__global__ void k_dft(const float* __restrict__ x, const float* __restrict__ tw,
                      float* __restrict__ xf) {
  __shared__ __align__(16) float Xs[16][128];
  __shared__ __align__(16) float TWs[16][64][2];
  const int b = blockIdx.z;
  const int f0 = blockIdx.y * 64;
  const int n0 = blockIdx.x * 128;
  const int tid = threadIdx.x;
  const int tn = tid & 15;   // n: n0 + tn*4 + {0..3} and n0 + 64 + tn*4 + {0..3}
  const int tf = tid >> 4;   // f: f0 + tf*4 + {0..3}
  const bool fvalid = (f0 + tf * 4) < FLEN;
  float ar[4][8] = {}, ai[4][8] = {};
  for (int t0 = 0; t0 < TT; t0 += 16) {
    __syncthreads();
    for (int l = tid; l < 512; l += 256) {
      int row = l >> 5, q = l & 31;
      int n = n0 + q * 4;
      const float* src = x + ((size_t)b * TT + (t0 + row)) * NN + n;
      float4 v = make_float4(0, 0, 0, 0);
      if (n + 3 < NN) v = *(const float4*)src;
      else {
        if (n + 0 < NN) v.x = src[0];
        if (n + 1 < NN) v.y = src[1];
        if (n + 2 < NN) v.z = src[2];
        if (n + 3 < NN) v.w = src[3];
      }
      *(float4*)&Xs[row][q * 4] = v;
    }
    for (int l = tid; l < 512; l += 256) {
      int row = l >> 5, fq = l & 31;   // f pair: f0 + fq*2, f0 + fq*2 + 1
      int f = f0 + fq * 2;
      float4 v = make_float4(0, 0, 0, 0);
      if (f < FLEN) {
        float2 cs = *(const float2*)&tw[((size_t)(t0 + row) * FLEN + f) * 2];
        v.x = cs.x; v.y = cs.y;
        if (f + 1 < FLEN) {
          float2 cs1 = *(const float2*)&tw[((size_t)(t0 + row) * FLEN + f + 1) * 2];
          v.z = cs1.x; v.w = cs1.y;
        }
      }
      *(float4*)&TWs[row][fq * 2][0] = v;
    }
    __syncthreads();
    if (fvalid) {
#pragma unroll 4
      for (int t = 0; t < 16; ++t) {
        float4 xv0 = *(float4*)&Xs[t][tn * 4];
        float4 xv1 = *(float4*)&Xs[t][64 + tn * 4];
        float xx[8] = {xv0.x, xv0.y, xv0.z, xv0.w, xv1.x, xv1.y, xv1.z, xv1.w};
        float4 p0 = *(float4*)&TWs[t][tf * 4][0];
        float4 p1 = *(float4*)&TWs[t][tf * 4 + 2][0];
        float c[4] = {p0.x, p0.z, p1.x, p1.z};
        float s[4] = {p0.y, p0.w, p1.y, p1.w};
#pragma unroll
        for (int i = 0; i < 4; ++i)
#pragma unroll
          for (int j = 0; j < 8; ++j) {
            ar[i][j] = fmaf(xx[j], c[i], ar[i][j]);
            ai[i][j] = fmaf(xx[j], s[i], ai[i][j]);
          }
      }
    }
  }
#pragma unroll
  for (int i = 0; i < 4; ++i) {
    int f = f0 + tf * 4 + i;
    if (f >= FLEN) continue;
    float* dst = &xf[((size_t)b * FLEN + f) * NN];
    float o[8];
#pragma unroll
    for (int j = 0; j < 8; ++j)
      o[j] = sqrtf(ar[i][j] * ar[i][j] + ai[i][j] * ai[i][j]);
    int n = n0 + tn * 4;   // <= 1983 always in-bounds
    *(float4*)&dst[n] = make_float4(o[0], o[1], o[2], o[3]);
    int n2 = n0 + 64 + tn * 4;
    if (n2 + 3 < NN) *(float4*)&dst[n2] = make_float4(o[4], o[5], o[6], o[7]);
    else {
#pragma unroll
      for (int j = 0; j < 4; ++j) if (n2 + j < NN) dst[n2 + j] = o[j + 4];
    }
  }
}

__global__ void k_colnorm(const float* __restrict__ xf, float* __restrict__ icn) {
  __shared__ float sc[4];
  int bf = blockIdx.x;
  const float* rowp = xf + (size_t)bf * NN;
  float s = 0.f;
  for (int i = threadIdx.x; i < NN; i += 256) { float v = rowp[i]; s = fmaf(v, v, s); }
  s = wredSum(s);
  int lane = threadIdx.x & 63, w = threadIdx.x >> 6;
  if (lane == 0) sc[w] = s;
  __syncthreads();
  if (threadIdx.x == 0)
    icn[bf] = 1.f / fmaxf(sqrtf(sc[0] + sc[1] + sc[2] + sc[3]), 1e-12f);
}

// k_xe with k_rownorm FOLDED IN: threads 0..63 compute irn for this block's 64
// n-values with the exact sequential f-loop k_rownorm used (same reads, same
// order -> bit-identical irn), then the GEMM epilogue consumes it from LDS.
__global__ void k_xe(const float* __restrict__ xf, const float* __restrict__ icn,
                     const float* __restrict__ Ex, float* __restrict__ xe) {
  __shared__ __align__(16) float As[16][64];
  __shared__ __align__(16) float Bs[16][128];
  __shared__ float irn_s[64];
  const int b = blockIdx.y;
  const int n0 = blockIdx.x * 64;
  const int tid = threadIdx.x;
  const int tn = tid >> 4, te = tid & 15;
  // rownorm pre-phase (bit-identical to the old k_rownorm)
  if (tid < 64) {
    int n = n0 + tid;
    if (n < NN) {
      float s = 0.f;
      for (int f = 0; f < FLEN; ++f) {
        float v = xf[((size_t)b * FLEN + f) * NN + n] * icn[b * FLEN + f];
        s = fmaf(v, v, s);
      }
      irn_s[tid] = 1.f / fmaxf(sqrtf(s), 1e-12f);
    }
  }
  float acc[4][8] = {};
  for (int f0 = 0; f0 < 160; f0 += 16) {
    __syncthreads();
    {
      int kt = tid >> 4, q = tid & 15;
      int f = f0 + kt;
      int n = n0 + q * 4;
      float4 v = make_float4(0, 0, 0, 0);
      if (f < FLEN) {
        float ic = icn[b * FLEN + f];
        const float* src = &xf[((size_t)b * FLEN + f) * NN + n];
        if (n + 3 < NN) v = *(const float4*)src;
        else {
          if (n + 0 < NN) v.x = src[0];
          if (n + 1 < NN) v.y = src[1];
          if (n + 2 < NN) v.z = src[2];
          if (n + 3 < NN) v.w = src[3];
        }
        v.x *= ic; v.y *= ic; v.z *= ic; v.w *= ic;
      }
      *(float4*)&As[kt][q * 4] = v;
    }
    for (int l = tid; l < 512; l += 256) {
      int kt = l >> 5, q = l & 31;
      int f = f0 + kt;
      float4 v = make_float4(0, 0, 0, 0);
      if (f < FLEN) v = *(const float4*)&Ex[(size_t)f * EE + q * 4];
      *(float4*)&Bs[kt][q * 4] = v;
    }
    __syncthreads();
#pragma unroll
    for (int k = 0; k < 16; ++k) {
      float4 a  = *(float4*)&As[k][tn * 4];
      float4 b0 = *(float4*)&Bs[k][te * 4];
      float4 b1 = *(float4*)&Bs[k][64 + te * 4];
      float av[4] = {a.x, a.y, a.z, a.w};
      float bv[8] = {b0.x, b0.y, b0.z, b0.w, b1.x, b1.y, b1.z, b1.w};
#pragma unroll
      for (int i = 0; i < 4; ++i)
#pragma unroll
        for (int j = 0; j < 8; ++j)
          acc[i][j] = fmaf(av[i], bv[j], acc[i][j]);
    }
  }
#pragma unroll
  for (int i = 0; i < 4; ++i) {
    int n = n0 + tn * 4 + i;
    if (n >= NN) continue;
    float sc = irn_s[tn * 4 + i];
    float* dst = &xe[((size_t)b * NN + n) * EE];
    *(float4*)&dst[te * 4] =
        make_float4(acc[i][0] * sc, acc[i][1] * sc, acc[i][2] * sc, acc[i][3] * sc);
    *(float4*)&dst[64 + te * 4] =
        make_float4(acc[i][4] * sc, acc[i][5] * sc, acc[i][6] * sc, acc[i][7] * sc);
  }
}

// x1 = relu([xe|nodes] . Wd[n]); emits x1 hi/lo fp16 fragment-tiled into dead xe region.
__global__ void k_x1(const float* xe, const float* __restrict__ nodes,
                     const float* __restrict__ Wd, float* __restrict__ x1,
                     ushort_t* x1hl) {
  __shared__ __align__(16) float xk[8][DKK];
  __shared__ float red[4][32][33];
  const int n = blockIdx.x;
  const int tid = threadIdx.x;
  {
    int b = tid >> 5, q = tid & 31;
    *(float4*)&xk[b][q * 4] = *(const float4*)&xe[((size_t)b * NN + n) * EE + q * 4];
  }
  if (tid < 128) {
    int b = tid >> 4, i = tid & 15;
    xk[b][EE + i] = nodes[(size_t)n * IDD + i];
  }
  __syncthreads();
  const int h4 = tid & 31;
  const int dg = tid >> 5;
  float acc[8][4] = {};
  for (int d = dg; d < DKK; d += 8) {
    float4 wv = *(const float4*)&Wd[((size_t)n * DKK + d) * HH + h4 * 4];
#pragma unroll
    for (int b = 0; b < 8; ++b) {
      float xv = xk[b][d];
      acc[b][0] = fmaf(xv, wv.x, acc[b][0]);
      acc[b][1] = fmaf(xv, wv.y, acc[b][1]);
      acc[b][2] = fmaf(xv, wv.z, acc[b][2]);
      acc[b][3] = fmaf(xv, wv.w, acc[b][3]);
    }
  }
#pragma unroll
  for (int b = 0; b < 8; ++b)
#pragma unroll
    for (int j = 0; j < 4; ++j)
      acc[b][j] += __shfl_xor(acc[b][j], 32, 64);
  const int wv_ = tid >> 6, lane = tid & 63;
  if (lane < 32) {
#pragma unroll
    for (int b = 0; b < 8; ++b)
#pragma unroll
      for (int j = 0; j < 4; ++j)
        red[wv_][lane][b * 4 + j] = acc[b][j];
  }
  __syncthreads();
  const size_t tbase = (size_t)(n >> 4) * 4096 + (size_t)(n & 15) * 8;
#pragma unroll
  for (int o = 0; o < 4; ++o) {
    int idx = tid + o * 256;
    int b = idx >> 7, h = idx & 127;
    float s = red[0][h >> 2][b * 4 + (h & 3)] + red[1][h >> 2][b * 4 + (h & 3)] +
              red[2][h >> 2][b * 4 + (h & 3)] + red[3][h >> 2][b * 4 + (h & 3)];
    s = fmaxf(s, 0.f);
    x1[((size_t)b * NN + n) * HH + h] = s;
    ushort_t hi, lo;
    split16(s, hi, lo);
    size_t slot = (size_t)b * (125 * 4096) + tbase +
                  (size_t)((h >> 5) * 512 + ((h >> 3) & 3) * 128 + (h & 7));
    x1hl[slot] = hi;
    x1hl[slot + 2048] = lo;
  }
}

__global__ void k_ln_stats(const float* __restrict__ x1, float* __restrict__ lns) {
  __shared__ float sc[4], sc2[4];
  int b = blockIdx.y, chunk = blockIdx.x;
  const float* base = x1 + (size_t)b * NN * HH + (size_t)chunk * 8000;
  float s = 0.f, s2 = 0.f;
  for (int i = threadIdx.x; i < 8000; i += 256) {
    float v = base[i];
    s += v; s2 = fmaf(v, v, s2);
  }
  s = wredSum(s); s2 = wredSum(s2);
  int lane = threadIdx.x & 63, w = threadIdx.x >> 6;
  if (lane == 0) { sc[w] = s; sc2[w] = s2; }
  __syncthreads();
  if (threadIdx.x == 0) {
    atomicAdd(&lns[b], sc[0] + sc[1] + sc[2] + sc[3]);
    atomicAdd(&lns[8 + b], sc2[0] + sc2[1] + sc2[2] + sc2[3]);
  }
}

// adp = ((x1 . Wx) - mu*colsumW) * inv_sd, fp16 hi/lo fragment-tiled.
// LN-final (mu/isd from raw sums) inlined -- bit-identical arithmetic.
__global__ void k_adp(const float* __restrict__ x1, const float* __restrict__ Wx,
                      const float* __restrict__ csw, const float* __restrict__ lns,
                      ushort_t* __restrict__ adphl) {
  __shared__ __align__(16) float As[16][64];
  __shared__ __align__(16) float Bs[16][128];
  const int r0 = blockIdx.x * 64;
  const int tid = threadIdx.x;
  const int tn = tid >> 4, te = tid & 15;
  float acc[4][8] = {};
  for (int k0 = 0; k0 < HH; k0 += 16) {
    __syncthreads();
    {
      int rr = tid >> 2, kq = tid & 3;
      float4 v = *(const float4*)&x1[(size_t)(r0 + rr) * HH + k0 + kq * 4];
      As[kq * 4 + 0][rr] = v.x;
      As[kq * 4 + 1][rr] = v.y;
      As[kq * 4 + 2][rr] = v.z;
      As[kq * 4 + 3][rr] = v.w;
    }
    for (int l = tid; l < 512; l += 256) {
      int kt = l >> 5, q = l & 31;
      *(float4*)&Bs[kt][q * 4] = *(const float4*)&Wx[(size_t)(k0 + kt) * HH + q * 4];
    }
    __syncthreads();
#pragma unroll
    for (int k = 0; k < 16; ++k) {
      float4 a  = *(float4*)&As[k][tn * 4];
      float4 b0 = *(float4*)&Bs[k][te * 4];
      float4 b1 = *(float4*)&Bs[k][64 + te * 4];
      float av[4] = {a.x, a.y, a.z, a.w};
      float bv[8] = {b0.x, b0.y, b0.z, b0.w, b1.x, b1.y, b1.z, b1.w};
#pragma unroll
      for (int i = 0; i < 4; ++i)
#pragma unroll
        for (int j = 0; j < 8; ++j)
          acc[i][j] = fmaf(av[i], bv[j], acc[i][j]);
    }
  }
  float4 c0 = *(const float4*)&csw[te * 4];
  float4 c1 = *(const float4*)&csw[64 + te * 4];
  float cw[8] = {c0.x, c0.y, c0.z, c0.w, c1.x, c1.y, c1.z, c1.w};
  const int c0k = te * 4, c1k = 64 + te * 4;
  const size_t o0r = (size_t)((c0k >> 5) * 512 + ((c0k >> 3) & 3) * 128 + (c0k & 7));
  const size_t o1r = (size_t)((c1k >> 5) * 512 + ((c1k >> 3) & 3) * 128 + (c1k & 7));
#pragma unroll
  for (int i = 0; i < 4; ++i) {
    int r = r0 + tn * 4 + i;
    int b = r / NN, n = r % NN;
    float cnt = (float)(NN * HH);
    float mu = lns[b] / cnt;
    float var = fmaxf(lns[8 + b] / cnt - mu * mu, 0.f);
    float isd = 1.f / sqrtf(var + 1e-8f);
    ushort_t hi[8], lo[8];
#pragma unroll
    for (int j = 0; j < 8; ++j) {
      float o = (acc[i][j] - mu * cw[j]) * isd;
      split16(o, hi[j], lo[j]);
    }
    size_t slot = (size_t)b * (125 * 4096) + (size_t)(n >> 4) * 4096 +
                  (size_t)(n & 15) * 8;
    ushort4 u;
    u.x = hi[0]; u.y = hi[1]; u.z = hi[2]; u.w = hi[3];
    *(ushort4*)&adphl[slot + o0r] = u;
    u.x = hi[4]; u.y = hi[5]; u.z = hi[6]; u.w = hi[7];
    *(ushort4*)&adphl[slot + o1r] = u;
    u.x = lo[0]; u.y = lo[1]; u.z = lo[2]; u.w = lo[3];
    *(ushort4*)&adphl[slot + 2048 + o0r] = u;
    u.x = lo[4]; u.y = lo[5]; u.z = lo[6]; u.w = lo[7];
    *(ushort4*)&adphl[slot + 2048 + o1r] = u;
  }
}

// ================= adj GEMM -> relu -> out (fp32, in place in d_out) ==========
// 32 A-rows per block (two A-tiles share every B fragment): halves B L2
// traffic (256->129 MB) and doubles MFMA per load; two independent MFMA
// chains give pipe ILP. launch_bounds(256,1) so the ~160-VGPR budget isn't
// throttled (round-2 lesson: VGPR cap silently kills the prefetch).
// Per-row MFMA chain identical to the proven k_adjT -> bit-identical adj.
__global__ __launch_bounds__(256, 1) void k_adjT(
    const ushort_t* __restrict__ adphl, const ushort_t* __restrict__ x1hl,
    float* __restrict__ out) {
  const int b = blockIdx.z;
  const int tA0 = blockIdx.y * 2;      // 0..124 even
  const int tA1 = tA0 + 1;             // may be 125 (invalid -> masked)
  const int tid = threadIdx.x;
  const int w = tid >> 6;
  const int lane = tid & 63;
  const int quad = lane >> 4, r16 = lane & 15;
  const int lq = quad * 128 + r16 * 8;
  const bool t1v = (tA1 <= 124);
  const int tA1c = t1v ? tA1 : 124;

  half8 A0h[4], A0l[4], A1h[4], A1l[4];
  {
    const ushort_t* a0 = adphl + ((size_t)(b * 125 + tA0)) * 4096 + lq;
    const ushort_t* a1 = adphl + ((size_t)(b * 125 + tA1c)) * 4096 + lq;
#pragma unroll
    for (int ks = 0; ks < 4; ++ks) {
      A0h[ks] = *(const half8*)(a0 + ks * 512);
      A0l[ks] = *(const half8*)(a0 + 2048 + ks * 512);
      A1h[ks] = *(const half8*)(a1 + ks * 512);
      A1l[ks] = *(const half8*)(a1 + 2048 + ks * 512);
    }
  }
  const int mbase = blockIdx.x * 512 + w * 128;  // 8 subtiles of 16
  const ushort_t* Bb = x1hl + (size_t)b * (125 * 4096) + lq;
  float* o0 = out + ((size_t)b * NN + tA0 * 16 + quad * 4) * NN;
  float* o1 = out + ((size_t)b * NN + (size_t)(t1v ? tA1 * 16 : 0) + quad * 4) * NN;

  half8 Bh0[4], Bl0[4], Bh1[4], Bl1[4];

#define LOADB(I, BH, BL)                                                      \
  {                                                                           \
    int tB_ = (mbase + (I) * 16) >> 4;                                        \
    if (tB_ > 124) tB_ = 124; /* m-subtiles >=2000 are store-masked */        \
    const ushort_t* bb_ = Bb + (size_t)tB_ * 4096;                            \
    BH[0] = *(const half8*)(bb_);        BL[0] = *(const half8*)(bb_ + 2048); \
    BH[1] = *(const half8*)(bb_ + 512);  BL[1] = *(const half8*)(bb_ + 2560); \
    BH[2] = *(const half8*)(bb_ + 1024); BL[2] = *(const half8*)(bb_ + 3072); \
    BH[3] = *(const half8*)(bb_ + 1536); BL[3] = *(const half8*)(bb_ + 3584); \
  }

#define STEP(I, BH, BL, BH2, BL2)                                             \
  {                                                                           \
    if ((I) < 7) LOADB((I) + 1, BH2, BL2);                                    \
    __builtin_amdgcn_sched_barrier(0); /* pin prefetch above the MFMAs */     \
    f32x4 acc0 = (f32x4){0.f, 0.f, 0.f, 0.f};                                 \
    f32x4 acc1 = (f32x4){0.f, 0.f, 0.f, 0.f};                                 \
    _Pragma("unroll")                                                         \
    for (int ks = 0; ks < 4; ++ks) {                                          \
      acc0 = __builtin_amdgcn_mfma_f32_16x16x32_f16(A0h[ks], BH[ks], acc0, 0, 0, 0); \
      acc0 = __builtin_amdgcn_mfma_f32_16x16x32_f16(A0h[ks], BL[ks], acc0, 0, 0, 0); \
      acc0 = __builtin_amdgcn_mfma_f32_16x16x32_f16(A0l[ks], BH[ks], acc0, 0, 0, 0); \
      acc1 = __builtin_amdgcn_mfma_f32_16x16x32_f16(A1h[ks], BH[ks], acc1, 0, 0, 0); \
      acc1 = __builtin_amdgcn_mfma_f32_16x16x32_f16(A1h[ks], BL[ks], acc1, 0, 0, 0); \
      acc1 = __builtin_amdgcn_mfma_f32_16x16x32_f16(A1l[ks], BH[ks], acc1, 0, 0, 0); \
    }                                                                         \
    int mt_ = mbase + (I) * 16 + r16;                                         \
    if (mt_ < NN) {                                                           \
      _Pragma("unroll")                                                       \
      for (int reg = 0; reg < 4; ++reg)                                       \
        o0[(size_t)reg * NN + mt_] = fmaxf(acc0[reg], 0.f);                   \
      if (t1v) {                                                              \
        _Pragma("unroll")                                                     \
        for (int reg = 0; reg < 4; ++reg)                                     \
          o1[(size_t)reg * NN + mt_] = fmaxf(acc1[reg], 0.f);                 \
      }                                                                       \
    }                                                                         \
  }

  LOADB(0, Bh0, Bl0);
  STEP(0, Bh0, Bl0, Bh1, Bl1);
  STEP(1, Bh1, Bl1, Bh0, Bl0);
  STEP(2, Bh0, Bl0, Bh1, Bl1);
  STEP(3, Bh1, Bl1, Bh0, Bl0);
  STEP(4, Bh0, Bl0, Bh1, Bl1);
  STEP(5, Bh1, Bl1, Bh0, Bl0);
  STEP(6, Bh0, Bl0, Bh1, Bl1);
  STEP(7, Bh1, Bl1, Bh0, Bl0);
#undef STEP
#undef LOADB
}

// ================= per-row topk-mask + softmax, in place on d_out =============
// One wave per row, 4 waves/block, 16000 independent waves; row lives in
// registers (V[8] f32x4). topk-20: positive-count -> threshold bisection into
// [20,64] candidates -> ballot-compact to per-wave LDS -> 64-wide bitonic
// sort -> t20 = rank-19 value. No block barriers.
__global__ __launch_bounds__(256, 4) void k_topsm(float* out) {
  __shared__ float scrV[4][64];
  __shared__ int scrI[4][64];
  const int tid = threadIdx.x;
  const int w = tid >> 6, lane = tid & 63;
  const int r = blockIdx.x * 4 + w;  // 0..15999
  float* g = out + (size_t)r * NN;

  f32x4 V[8];  // lane's 32 values: m = j*256 + lane*4 + e
#pragma unroll
  for (int j = 0; j < 8; ++j) {
    int m0 = j * 256 + lane * 4;
    if (m0 < NN) V[j] = *(const f32x4*)&g[m0];
    else V[j] = (f32x4){-1.f, -1.f, -1.f, -1.f};
  }

  float mx = -1.f, cp = 0.f;
#pragma unroll
  for (int j = 0; j < 8; ++j)
#pragma unroll
    for (int e = 0; e < 4; ++e) {
      mx = fmaxf(mx, V[j][e]);
      cp += (V[j][e] > 0.f) ? 1.f : 0.f;
    }
  const float m = wredMaxAll(mx);  // >= 0 (relu)
  const float cpos = wredSumAll(cp);
  const float em = expf(-m);

  if (cpos <= 20.5f) {
    // all positives are in the top-20; zero-ties give identical output
    float s = 0.f;
#pragma unroll
    for (int j = 0; j < 8; ++j)
#pragma unroll
      for (int e = 0; e < 4; ++e)
        if (V[j][e] > 0.f) s += expf(V[j][e] - m);
    s = wredSumAll(s);
    const float invD = 1.f / (s + (2000.f - cpos) * em);
    const float defv = em * invD;
#pragma unroll
    for (int j = 0; j < 8; ++j) {
      int m0 = j * 256 + lane * 4;
      if (m0 >= NN) continue;
      float4 o;
      o.x = (V[j][0] > 0.f) ? expf(V[j][0] - m) * invD : defv;
      o.y = (V[j][1] > 0.f) ? expf(V[j][1] - m) * invD : defv;
      o.z = (V[j][2] > 0.f) ? expf(V[j][2] - m) * invD : defv;
      o.w = (V[j][3] > 0.f) ? expf(V[j][3] - m) * invD : defv;
      *(float4*)&g[m0] = o;
    }
  } else {
    // bracket candidate count into [20,64]
    float tval = 0.f, cf = cpos;
    if (cpos > 64.5f) {
      float tlo = 0.f, thi = m;
      bool found = false;
      for (int it = 0; it < 64 && !found; ++it) {
        float mid = (it < 12)
            ? 0.5f * (tlo + thi)
            : __uint_as_float((__float_as_uint(tlo) + __float_as_uint(thi)) >> 1);
        float c = 0.f;
#pragma unroll
        for (int j = 0; j < 8; ++j)
#pragma unroll
          for (int e = 0; e < 4; ++e)
            c += (V[j][e] > mid) ? 1.f : 0.f;
        c = wredSumAll(c);
        if (c > 64.5f) tlo = mid;
        else if (c < 19.5f) thi = mid;
        else { tval = mid; cf = c; found = true; }
      }
      if (!found) { tval = tlo; cf = 64.f; }  // unreachable for distinct floats
    }
    int cI = (int)(cf + 0.5f);
    if (cI > 64) cI = 64;

    // ballot-compact candidates {v > tval} into per-wave LDS scratch
    float* sv = scrV[w];
    int* si = scrI[w];
    int base = 0;
#pragma unroll
    for (int j = 0; j < 8; ++j)
#pragma unroll
      for (int e = 0; e < 4; ++e) {
        bool p = V[j][e] > tval;
        unsigned long long msk = __ballot(p);
        if (p) {
          int pos = base + (int)__popcll(msk & ((1ull << lane) - 1ull));
          if (pos < 64) { sv[pos] = V[j][e]; si[pos] = j * 256 + lane * 4 + e; }
        }
        base += (int)__popcll(msk);
      }
    asm volatile("s_waitcnt lgkmcnt(0)" ::: "memory");

    float cv = (lane < cI) ? sv[lane] : -1.f;
    int ci = (lane < cI) ? si[lane] : 0x7fffffff;
    // bitonic sort, descending (ties -> lower index first)
#pragma unroll
    for (int k = 2; k <= 64; k <<= 1)
#pragma unroll
      for (int j = k >> 1; j > 0; j >>= 1) {
        float ov = __shfl_xor(cv, j, 64);
        int oi = __shfl_xor(ci, j, 64);
        bool otherBetter = (ov > cv) || (ov == cv && oi < ci);
        bool iAmLow = (lane & j) == 0;
        bool desc = (lane & k) == 0;
        bool take = (desc == iAmLow) ? otherBetter : !otherBetter;
        if (take) { cv = ov; ci = oi; }
      }
    const float t20 = __shfl(cv, 19, 64);  // 20th largest (cI >= 20)
    float e20 = (lane < 20) ? expf(cv - m) : 0.f;
    const float s20 = wredSumAll(e20);
    const float invD = 1.f / (s20 + (2000.f - 20.f) * em);
    const float defv = em * invD;
#pragma unroll
    for (int j = 0; j < 8; ++j) {
      int m0 = j * 256 + lane * 4;
      if (m0 >= NN) continue;
      float4 o;
      o.x = (V[j][0] >= t20) ? expf(V[j][0] - m) * invD : defv;
      o.y = (V[j][1] >= t20) ? expf(V[j][1] - m) * invD : defv;
      o.z = (V[j][2] >= t20) ? expf(V[j][2] - m) * invD : defv;
      o.w = (V[j][3] >= t20) ? expf(V[j][3] - m) * invD : defv;
      *(float4*)&g[m0] = o;
    }
  }
}

extern "C" void kernel_launch(void* const* d_in, const int* in_sizes, int n_in,
                              void* d_out, int out_size, void* d_ws, size_t ws_size,
                              hipStream_t stream) {
  const float* x     = (const float*)d_in[0];
  const float* Ex    = (const float*)d_in[1];
  const float* nodes = (const float*)d_in[2];
  const float* Wd    = (const float*)d_in[3];
  const float* Wx    = (const float*)d_in[4];
  float* out = (float*)d_out;
  float* w = (float*)d_ws;
  float* tw  = w + OFF_TW;
  float* xf  = w + OFF_XF;
  float* icn = w + OFF_ICN;
  float* xe  = w + OFF_XE;
  float* x1  = w + OFF_X1;
  float* csw = w + OFF_CSW;
  float* lns = w + OFF_LNS;
  ushort_t* adphl = (ushort_t*)(w + OFF_ADP);
  ushort_t* x1hl  = (ushort_t*)(w + OFF_XE);  // reuses dead xe region

  k_tw<<<(TT * FLEN + 255) / 256, 256, 0, stream>>>(Wx, tw, csw, lns);
  k_dft<<<dim3(16, 3, BB), 256, 0, stream>>>(x, tw, xf);
  k_colnorm<<<BB * FLEN, 256, 0, stream>>>(xf, icn);
  k_xe<<<dim3(32, BB), 256, 0, stream>>>(xf, icn, Ex, xe);
  k_x1<<<NN, 256, 0, stream>>>(xe, nodes, Wd, x1, x1hl);
  k_ln_stats<<<dim3(32, BB), 256, 0, stream>>>(x1, lns);
  k_adp<<<250, 256, 0, stream>>>(x1, Wx, csw, lns, adphl);
  k_adjT<<<dim3(4, 63, BB), 256, 0, stream>>>(adphl, x1hl, out);
  k_topsm<<<(BB * NN) / 4, 256, 0, stream>>>(out);
}